// Round 1
// baseline (2170.831 us; speedup 1.0000x reference)
//
#include <hip/hip_runtime.h>
#include <stdint.h>

// Problem constants
#define BB 2
#define TT 2048
#define DD 2048
#define HH 16
#define HD 2048     // H*Dk = H*Dv
#define MM 4096     // B*T

typedef float f32x4 __attribute__((ext_vector_type(4)));
typedef __bf16 bf16x8 __attribute__((ext_vector_type(8)));
typedef unsigned short u16x4 __attribute__((ext_vector_type(4)));

__device__ __forceinline__ unsigned short f2b(float f) {
  unsigned int u = __float_as_uint(f);
  u += 0x7FFFu + ((u >> 16) & 1u);   // RNE
  return (unsigned short)(u >> 16);
}

__device__ __forceinline__ void async_ld16(const void* g, void* l) {
  typedef __attribute__((address_space(3))) void as3_t;
  typedef const __attribute__((address_space(1))) void as1_t;
  // int-cast route (CK-style): generic LDS addr low 32 bits == LDS offset
  __builtin_amdgcn_global_load_lds((as1_t*)(uintptr_t)g,
                                   (as3_t*)(unsigned int)(uintptr_t)l, 16, 0, 0);
}

// ---------------- cast f32 -> bf16 (vectorized x4) ----------------
__global__ __launch_bounds__(256) void cast_f32_bf16(const float* __restrict__ in,
                                                     unsigned short* __restrict__ out,
                                                     int n4) {
  int i = blockIdx.x * 256 + threadIdx.x;
  if (i >= n4) return;
  f32x4 v = *(const f32x4*)(in + (size_t)i * 4);
  u16x4 r;
  #pragma unroll
  for (int j = 0; j < 4; j++) r[j] = f2b(v[j]);
  *(u16x4*)(out + (size_t)i * 4) = r;
}

// ---------------- transpose + cast: in f32 [R,C] -> out bf16 [C,R] ----------------
__global__ __launch_bounds__(256) void transpose_cast(const float* __restrict__ in,
                                                      unsigned short* __restrict__ out,
                                                      int R, int C) {
  __shared__ float tile[32][33];
  int bx = blockIdx.x * 32, by = blockIdx.y * 32;
  int tx = threadIdx.x, ty = threadIdx.y;
  #pragma unroll
  for (int i = 0; i < 32; i += 8)
    tile[ty + i][tx] = in[(size_t)(by + ty + i) * C + bx + tx];
  __syncthreads();
  #pragma unroll
  for (int i = 0; i < 32; i += 8)
    out[(size_t)(bx + ty + i) * R + by + tx] = f2b(tile[tx][ty + i]);
}

// ---------------- bf16 GEMM: C[M,N] f32 = A[M,K] @ Bt[N,K]^T (+bias) ----------------
// m97 structure: 128x128 tile, BK=32, global_load_lds(16B), 16x16x32 MFMA, 4 waves 2x2.
__global__ __launch_bounds__(256) void gemm_bf16(const unsigned short* __restrict__ A,
                                                 const unsigned short* __restrict__ Bt,
                                                 float* __restrict__ C,
                                                 const float* __restrict__ bias,
                                                 int M, int N, int K) {
  __shared__ __align__(16) unsigned short As[128 * 32];
  __shared__ __align__(16) unsigned short Bs[128 * 32];
  int tid = threadIdx.x;
  int l = tid & 63, w = tid >> 6;
  int row0 = blockIdx.y * 128, col0 = blockIdx.x * 128;
  int wm = (w >> 1) * 64, wn = (w & 1) * 64;
  const f32x4 fz = {0.f, 0.f, 0.f, 0.f};
  f32x4 acc[4][4];
  #pragma unroll
  for (int i = 0; i < 4; i++)
    #pragma unroll
    for (int j = 0; j < 4; j++) acc[i][j] = fz;

  int srow = l >> 2, skoff = (l & 3) * 8;   // staging: row within chunk, k offset
  int quad = l >> 4, mrow = l & 15;         // fragment indices

  for (int kt = 0; kt < K; kt += 32) {
    #pragma unroll
    for (int i = 0; i < 2; i++) {
      int c = w * 2 + i;                     // chunk = 16 rows of the 128-row tile
      const unsigned short* gA = A + (size_t)(row0 + c * 16 + srow) * K + kt + skoff;
      const unsigned short* gB = Bt + (size_t)(col0 + c * 16 + srow) * K + kt + skoff;
      async_ld16(gA, As + c * 512);
      async_ld16(gB, Bs + c * 512);
    }
    __syncthreads();
    bf16x8 af[4], bfr[4];
    #pragma unroll
    for (int i = 0; i < 4; i++)
      af[i] = *(const bf16x8*)(As + (wm + i * 16 + mrow) * 32 + quad * 8);
    #pragma unroll
    for (int j = 0; j < 4; j++)
      bfr[j] = *(const bf16x8*)(Bs + (wn + j * 16 + mrow) * 32 + quad * 8);
    #pragma unroll
    for (int i = 0; i < 4; i++)
      #pragma unroll
      for (int j = 0; j < 4; j++)
        acc[i][j] = __builtin_amdgcn_mfma_f32_16x16x32_bf16(af[i], bfr[j], acc[i][j], 0, 0, 0);
    __syncthreads();
  }
  // epilogue: D row = quad*4+reg, col = lane&15  (m89-verified layout)
  #pragma unroll
  for (int i = 0; i < 4; i++) {
    #pragma unroll
    for (int j = 0; j < 4; j++) {
      #pragma unroll
      for (int r = 0; r < 4; r++) {
        int rr = row0 + wm + i * 16 + quad * 4 + r;
        int cc = col0 + wn + j * 16 + mrow;
        float v = acc[i][j][r];
        if (bias) v += bias[cc];
        C[(size_t)rr * N + cc] = v;
      }
    }
  }
}

// ---------------- causal depthwise conv(K=4) + SiLU (+ per-head l2norm) ----------------
__global__ __launch_bounds__(256) void conv_silu_kernel(const float* __restrict__ Pre,
                                                        const float* __restrict__ cw,
                                                        float* __restrict__ outp,
                                                        int do_norm) {
  int bt = blockIdx.x;
  int b = bt / TT, t = bt - b * TT;
  int tid = threadIdx.x;
  int ch0 = tid * 8;
  f32x4 wv[8];
  #pragma unroll
  for (int j = 0; j < 8; j++) wv[j] = *(const f32x4*)(cw + (size_t)(ch0 + j) * 4);
  float acc[8] = {0, 0, 0, 0, 0, 0, 0, 0};
  #pragma unroll
  for (int i = 0; i < 4; i++) {
    int tt = t - 3 + i;
    if (tt < 0) continue;                 // uniform branch (block-level t)
    const float* r = Pre + ((size_t)(b * TT + tt)) * HD + ch0;
    f32x4 a0 = *(const f32x4*)r;
    f32x4 a1 = *(const f32x4*)(r + 4);
    #pragma unroll
    for (int j = 0; j < 4; j++) {
      acc[j]     += a0[j] * wv[j][i];
      acc[4 + j] += a1[j] * wv[4 + j][i];
    }
  }
  float val[8];
  #pragma unroll
  for (int j = 0; j < 8; j++) val[j] = acc[j] / (1.f + expf(-acc[j]));   // SiLU
  if (do_norm) {                          // l2norm over 128 ch/head: 16 lanes x 8 ch
    float ss = 0.f;
    #pragma unroll
    for (int j = 0; j < 8; j++) ss += val[j] * val[j];
    ss += __shfl_xor(ss, 1); ss += __shfl_xor(ss, 2);
    ss += __shfl_xor(ss, 4); ss += __shfl_xor(ss, 8);
    float rs = rsqrtf(ss + 1e-6f);
    #pragma unroll
    for (int j = 0; j < 8; j++) val[j] *= rs;
  }
  float* op = outp + (size_t)bt * HD + ch0;
  f32x4 o0, o1;
  #pragma unroll
  for (int j = 0; j < 4; j++) { o0[j] = val[j]; o1[j] = val[4 + j]; }
  *(f32x4*)op = o0;
  *(f32x4*)(op + 4) = o1;
}

// ---------------- beta = sigmoid(x @ Wb) ----------------
__global__ __launch_bounds__(256) void beta_kernel(const float* __restrict__ x,
                                                   const float* __restrict__ Wb,
                                                   float* __restrict__ beta) {
  __shared__ float xs[2048];
  int bt = blockIdx.x, tid = threadIdx.x;
  const float* row = x + (size_t)bt * DD;
  #pragma unroll
  for (int i = 0; i < 2; i++)
    *(f32x4*)(xs + tid * 8 + i * 4) = *(const f32x4*)(row + tid * 8 + i * 4);
  __syncthreads();
  int h = tid >> 4, seg = tid & 15;
  float p = 0.f;
  for (int j = 0; j < 128; j++) {
    int d = seg * 128 + ((j + seg * 9) & 127);   // stagger: conflict-free banks
    p += xs[d] * Wb[(size_t)d * HH + h];
  }
  p += __shfl_xor(p, 1); p += __shfl_xor(p, 2);
  p += __shfl_xor(p, 4); p += __shfl_xor(p, 8);
  if (seg == 0) beta[(size_t)bt * HH + h] = 1.f / (1.f + expf(-p));
}

// ---------------- gexp = exp(-exp(A_log[h]) * softplus(g + dt_bias)) ----------------
__global__ __launch_bounds__(256) void gexp_kernel(const float* __restrict__ g,
                                                   const float* __restrict__ A_log,
                                                   const float* __restrict__ dt_bias,
                                                   float* __restrict__ ge, int n) {
  int i = blockIdx.x * 256 + threadIdx.x;
  if (i >= n) return;
  int ch = i & (HD - 1);
  int h = ch >> 7;
  float gv = g[i] + dt_bias[ch];
  float sp = (gv > 20.f) ? gv : log1pf(expf(gv));
  ge[i] = expf(-expf(A_log[h]) * sp);
}

// ---------------- KDA delta-rule scan: wave per 4 v-columns ----------------
// v and o may alias (same buffer): no __restrict__ on those.
__global__ __launch_bounds__(64) void scan_kernel(const float* __restrict__ q,
                                                  const float* __restrict__ k,
                                                  const float* v,
                                                  const float* __restrict__ ge,
                                                  const float* __restrict__ beta,
                                                  float* o) {
  int wid = blockIdx.x;            // B*H*32 waves
  int colgrp = wid & 31;
  int bh = wid >> 5;
  int h = bh & (HH - 1);
  int b = bh >> 4;
  int l = threadIdx.x;
  int col = (colgrp << 2) + (l >> 4);   // v column owned by this 16-lane group
  int koff = (l & 15) << 3;             // 8-wide k slice
  float s[8];
  #pragma unroll
  for (int j = 0; j < 8; j++) s[j] = 0.f;
  const float scale = 0.08838834764831845f;  // 128^-0.5
  size_t base = ((size_t)b * TT) * HD + (size_t)h * 128;
  size_t bbase = (size_t)b * TT * HH + h;
  for (int t = 0; t < TT; t++) {
    size_t ro = base + (size_t)t * HD;
    f32x4 k0 = *(const f32x4*)(k + ro + koff);
    f32x4 k1 = *(const f32x4*)(k + ro + koff + 4);
    f32x4 g0 = *(const f32x4*)(ge + ro + koff);
    f32x4 g1 = *(const f32x4*)(ge + ro + koff + 4);
    float vt = v[ro + col];
    float bt = beta[bbase + (size_t)t * HH];
    // decay + prediction partial
    float p = 0.f;
    #pragma unroll
    for (int j = 0; j < 4; j++) {
      s[j] *= g0[j];     p += k0[j] * s[j];
      s[4 + j] *= g1[j]; p += k1[j] * s[4 + j];
    }
    p += __shfl_xor(p, 1); p += __shfl_xor(p, 2);
    p += __shfl_xor(p, 4); p += __shfl_xor(p, 8);
    float u = (vt - p) * bt;
    f32x4 q0 = *(const f32x4*)(q + ro + koff);
    f32x4 q1 = *(const f32x4*)(q + ro + koff + 4);
    float po = 0.f;
    #pragma unroll
    for (int j = 0; j < 4; j++) {
      s[j] += k0[j] * u;     po += q0[j] * s[j];
      s[4 + j] += k1[j] * u; po += q1[j] * s[4 + j];
    }
    po += __shfl_xor(po, 1); po += __shfl_xor(po, 2);
    po += __shfl_xor(po, 4); po += __shfl_xor(po, 8);
    if ((l & 15) == 0) o[ro + col] = po * scale;
  }
}

// ---------------- gated RMSNorm -> bf16 ----------------
__global__ __launch_bounds__(256) void out_norm_kernel(const float* o,
                                                       const float* __restrict__ gate,
                                                       const float* __restrict__ w,
                                                       unsigned short* __restrict__ onb) {
  int bt = blockIdx.x, tid = threadIdx.x;
  int h = tid >> 4, seg = tid & 15;
  size_t base = (size_t)bt * HD + (size_t)h * 128 + seg * 8;
  f32x4 o0 = *(const f32x4*)(o + base);
  f32x4 o1 = *(const f32x4*)(o + base + 4);
  float ss = 0.f;
  #pragma unroll
  for (int j = 0; j < 4; j++) ss += o0[j] * o0[j] + o1[j] * o1[j];
  ss += __shfl_xor(ss, 1); ss += __shfl_xor(ss, 2);
  ss += __shfl_xor(ss, 4); ss += __shfl_xor(ss, 8);
  float rs = rsqrtf(ss * (1.f / 128.f) + 1e-5f);
  u16x4 r0, r1;
  #pragma unroll
  for (int j = 0; j < 4; j++) {
    float gv0 = gate[base + j];
    float gv1 = gate[base + 4 + j];
    float a0 = o0[j] * rs * w[seg * 8 + j] * (gv0 / (1.f + expf(-gv0)));
    float a1 = o1[j] * rs * w[seg * 8 + 4 + j] * (gv1 / (1.f + expf(-gv1)));
    r0[j] = f2b(a0);
    r1[j] = f2b(a1);
  }
  *(u16x4*)(onb + base) = r0;
  *(u16x4*)(onb + base + 4) = r1;
}

// ---------------- driver ----------------
extern "C" void kernel_launch(void* const* d_in, const int* in_sizes, int n_in,
                              void* d_out, int out_size, void* d_ws, size_t ws_size,
                              hipStream_t stream) {
  const float* x       = (const float*)d_in[0];
  const float* Wq      = (const float*)d_in[1];
  const float* Wk      = (const float*)d_in[2];
  const float* Wv      = (const float*)d_in[3];
  const float* cq      = (const float*)d_in[4];
  const float* ck      = (const float*)d_in[5];
  const float* cv      = (const float*)d_in[6];
  const float* Wf1     = (const float*)d_in[7];
  const float* Wf2     = (const float*)d_in[8];
  const float* Wb      = (const float*)d_in[9];
  const float* A_log   = (const float*)d_in[10];
  const float* dt_bias = (const float*)d_in[11];
  const float* Wg      = (const float*)d_in[12];
  const float* bg      = (const float*)d_in[13];
  const float* onw     = (const float*)d_in[14];
  const float* Wo      = (const float*)d_in[15];
  float* out = (float*)d_out;

  char* ws = (char*)d_ws;
  unsigned short* WT  = (unsigned short*)(ws);                       //  8 MB rotating W^T
  unsigned short* xb  = (unsigned short*)(ws + ((size_t)8  << 20));  // 16 MB bf16 x
  float* P    = (float*)(ws + ((size_t)24  << 20));                  // 32 MB rotating pre/gate
  float* qb   = (float*)(ws + ((size_t)56  << 20));                  // 32 MB
  float* kb   = (float*)(ws + ((size_t)88  << 20));                  // 32 MB
  float* vb   = (float*)(ws + ((size_t)120 << 20));                  // 32 MB (aliased by o)
  float* geb  = (float*)(ws + ((size_t)152 << 20));                  // 32 MB
  float* betab= (float*)(ws + ((size_t)184 << 20));                  // 256 KB
  float* f1   = (float*)(ws + ((size_t)185 << 20));                  //   2 MB
  unsigned short* f1b = (unsigned short*)(ws + ((size_t)187 << 20)); //   1 MB
  unsigned short* onb = xb;   // xb dead after gate GEMM
  float* gateb = P;           // P reused as gate buffer
  float* ob    = vb;          // scan output aliases v (safe: per-wave read-before-write)

  dim3 tb(32, 8);
  dim3 gemm_grid(HD / 128, MM / 128);

  // x -> bf16
  cast_f32_bf16<<<(MM * DD / 4 + 255) / 256, 256, 0, stream>>>(x, xb, MM * DD / 4);

  // q path
  transpose_cast<<<dim3(HD / 32, DD / 32), tb, 0, stream>>>(Wq, WT, DD, HD);
  gemm_bf16<<<gemm_grid, 256, 0, stream>>>(xb, WT, P, nullptr, MM, HD, DD);
  conv_silu_kernel<<<MM, 256, 0, stream>>>(P, cq, qb, 1);
  // k path
  transpose_cast<<<dim3(HD / 32, DD / 32), tb, 0, stream>>>(Wk, WT, DD, HD);
  gemm_bf16<<<gemm_grid, 256, 0, stream>>>(xb, WT, P, nullptr, MM, HD, DD);
  conv_silu_kernel<<<MM, 256, 0, stream>>>(P, ck, kb, 1);
  // v path
  transpose_cast<<<dim3(HD / 32, DD / 32), tb, 0, stream>>>(Wv, WT, DD, HD);
  gemm_bf16<<<gemm_grid, 256, 0, stream>>>(xb, WT, P, nullptr, MM, HD, DD);
  conv_silu_kernel<<<MM, 256, 0, stream>>>(P, cv, vb, 0);

  // beta
  beta_kernel<<<MM, 256, 0, stream>>>(x, Wb, betab);

  // g chain: f1 = x@Wf1 ; g = f1@Wf2 ; gexp
  transpose_cast<<<dim3(128 / 32, DD / 32), tb, 0, stream>>>(Wf1, WT, DD, 128);
  gemm_bf16<<<dim3(1, MM / 128), 256, 0, stream>>>(xb, WT, f1, nullptr, MM, 128, DD);
  cast_f32_bf16<<<(MM * 128 / 4 + 255) / 256, 256, 0, stream>>>(f1, f1b, MM * 128 / 4);
  transpose_cast<<<dim3(HD / 32, 128 / 32), tb, 0, stream>>>(Wf2, WT, 128, HD);
  gemm_bf16<<<gemm_grid, 256, 0, stream>>>(f1b, WT, P, nullptr, MM, HD, 128);
  gexp_kernel<<<(MM * HD + 255) / 256, 256, 0, stream>>>(P, A_log, dt_bias, geb, MM * HD);

  // gate = x@Wg + bg  (into P, which is free now)
  transpose_cast<<<dim3(HD / 32, DD / 32), tb, 0, stream>>>(Wg, WT, DD, HD);
  gemm_bf16<<<gemm_grid, 256, 0, stream>>>(xb, WT, gateb, bg, MM, HD, DD);

  // recurrent delta-rule scan
  scan_kernel<<<BB * HH * 32, 64, 0, stream>>>(qb, kb, vb, geb, betab, ob);

  // gated RMSNorm -> bf16
  out_norm_kernel<<<MM, 256, 0, stream>>>(ob, gateb, onw, onb);

  // final projection
  transpose_cast<<<dim3(DD / 32, HD / 32), tb, 0, stream>>>(Wo, WT, HD, DD);
  gemm_bf16<<<dim3(DD / 128, MM / 128), 256, 0, stream>>>(onb, WT, out, nullptr, MM, DD, HD);
}

// Round 2
// 1793.280 us; speedup vs baseline: 1.2105x; 1.2105x over previous
//
#include <hip/hip_runtime.h>
#include <stdint.h>

// Problem constants
#define BB 2
#define TT 2048
#define DD 2048
#define HH 16
#define HD 2048     // H*Dk = H*Dv
#define MM 4096     // B*T
#define SCH 16      // scan chunk steps

typedef float f32x4 __attribute__((ext_vector_type(4)));
typedef __bf16 bf16x8 __attribute__((ext_vector_type(8)));
typedef unsigned short u16x4 __attribute__((ext_vector_type(4)));

__device__ __forceinline__ unsigned short f2b(float f) {
  unsigned int u = __float_as_uint(f);
  u += 0x7FFFu + ((u >> 16) & 1u);   // RNE
  return (unsigned short)(u >> 16);
}

__device__ __forceinline__ void async_ld16(const void* g, void* l) {
  typedef __attribute__((address_space(3))) void as3_t;
  typedef const __attribute__((address_space(1))) void as1_t;
  // NOTE: LDS arg must be WAVE-UNIFORM base; HW adds lane*16 itself.
  __builtin_amdgcn_global_load_lds((as1_t*)(uintptr_t)g,
                                   (as3_t*)(unsigned int)(uintptr_t)l, 16, 0, 0);
}

// ---------------- cast f32 -> bf16 (vectorized x4) ----------------
__global__ __launch_bounds__(256) void cast_f32_bf16(const float* __restrict__ in,
                                                     unsigned short* __restrict__ out,
                                                     int n4) {
  int i = blockIdx.x * 256 + threadIdx.x;
  if (i >= n4) return;
  f32x4 v = *(const f32x4*)(in + (size_t)i * 4);
  u16x4 r;
  #pragma unroll
  for (int j = 0; j < 4; j++) r[j] = f2b(v[j]);
  *(u16x4*)(out + (size_t)i * 4) = r;
}

// ---------------- transpose + cast: in f32 [R,C] -> out bf16 [C,R] ----------------
__global__ __launch_bounds__(256) void transpose_cast(const float* __restrict__ in,
                                                      unsigned short* __restrict__ out,
                                                      int R, int C) {
  __shared__ float tile[32][33];
  int bx = blockIdx.x * 32, by = blockIdx.y * 32;
  int tx = threadIdx.x, ty = threadIdx.y;
  #pragma unroll
  for (int i = 0; i < 32; i += 8)
    tile[ty + i][tx] = in[(size_t)(by + ty + i) * C + bx + tx];
  __syncthreads();
  #pragma unroll
  for (int i = 0; i < 32; i += 8)
    out[(size_t)(bx + ty + i) * R + by + tx] = f2b(tile[tx][ty + i]);
}

// ---------------- bf16 GEMM: C[M,N] f32 = A[M,K] @ Bt[N,K]^T (+bias) ----------------
__global__ __launch_bounds__(256) void gemm_bf16(const unsigned short* __restrict__ A,
                                                 const unsigned short* __restrict__ Bt,
                                                 float* __restrict__ C,
                                                 const float* __restrict__ bias,
                                                 int M, int N, int K) {
  __shared__ __align__(16) unsigned short As[128 * 32];
  __shared__ __align__(16) unsigned short Bs[128 * 32];
  int tid = threadIdx.x;
  int l = tid & 63, w = tid >> 6;
  int row0 = blockIdx.y * 128, col0 = blockIdx.x * 128;
  int wm = (w >> 1) * 64, wn = (w & 1) * 64;
  const f32x4 fz = {0.f, 0.f, 0.f, 0.f};
  f32x4 acc[4][4];
  #pragma unroll
  for (int i = 0; i < 4; i++)
    #pragma unroll
    for (int j = 0; j < 4; j++) acc[i][j] = fz;

  int srow = l >> 2, skoff = (l & 3) * 8;
  int quad = l >> 4, mrow = l & 15;

  for (int kt = 0; kt < K; kt += 32) {
    #pragma unroll
    for (int i = 0; i < 2; i++) {
      int c = w * 2 + i;
      const unsigned short* gA = A + (size_t)(row0 + c * 16 + srow) * K + kt + skoff;
      const unsigned short* gB = Bt + (size_t)(col0 + c * 16 + srow) * K + kt + skoff;
      async_ld16(gA, As + c * 512);
      async_ld16(gB, Bs + c * 512);
    }
    __syncthreads();
    bf16x8 af[4], bfr[4];
    #pragma unroll
    for (int i = 0; i < 4; i++)
      af[i] = *(const bf16x8*)(As + (wm + i * 16 + mrow) * 32 + quad * 8);
    #pragma unroll
    for (int j = 0; j < 4; j++)
      bfr[j] = *(const bf16x8*)(Bs + (wn + j * 16 + mrow) * 32 + quad * 8);
    #pragma unroll
    for (int i = 0; i < 4; i++)
      #pragma unroll
      for (int j = 0; j < 4; j++)
        acc[i][j] = __builtin_amdgcn_mfma_f32_16x16x32_bf16(af[i], bfr[j], acc[i][j], 0, 0, 0);
    __syncthreads();
  }
  #pragma unroll
  for (int i = 0; i < 4; i++) {
    #pragma unroll
    for (int j = 0; j < 4; j++) {
      #pragma unroll
      for (int r = 0; r < 4; r++) {
        int rr = row0 + wm + i * 16 + quad * 4 + r;
        int cc = col0 + wn + j * 16 + mrow;
        float v = acc[i][j][r];
        if (bias) v += bias[cc];
        C[(size_t)rr * N + cc] = v;
      }
    }
  }
}

// ---------------- causal depthwise conv(K=4) + SiLU (+ per-head l2norm) ----------------
// Writes [B,H,T,128] layout for the scan.
__global__ __launch_bounds__(256) void conv_silu_kernel(const float* __restrict__ Pre,
                                                        const float* __restrict__ cw,
                                                        float* __restrict__ outp,
                                                        int do_norm) {
  int bt = blockIdx.x;
  int b = bt >> 11, t = bt & (TT - 1);
  int tid = threadIdx.x;
  int ch0 = tid * 8;
  f32x4 wv[8];
  #pragma unroll
  for (int j = 0; j < 8; j++) wv[j] = *(const f32x4*)(cw + (size_t)(ch0 + j) * 4);
  float acc[8] = {0, 0, 0, 0, 0, 0, 0, 0};
  #pragma unroll
  for (int i = 0; i < 4; i++) {
    int tt = t - 3 + i;
    if (tt < 0) continue;
    const float* r = Pre + ((size_t)(b * TT + tt)) * HD + ch0;
    f32x4 a0 = *(const f32x4*)r;
    f32x4 a1 = *(const f32x4*)(r + 4);
    #pragma unroll
    for (int j = 0; j < 4; j++) {
      acc[j]     += a0[j] * wv[j][i];
      acc[4 + j] += a1[j] * wv[4 + j][i];
    }
  }
  float val[8];
  #pragma unroll
  for (int j = 0; j < 8; j++) val[j] = acc[j] / (1.f + expf(-acc[j]));   // SiLU
  if (do_norm) {
    float ss = 0.f;
    #pragma unroll
    for (int j = 0; j < 8; j++) ss += val[j] * val[j];
    ss += __shfl_xor(ss, 1); ss += __shfl_xor(ss, 2);
    ss += __shfl_xor(ss, 4); ss += __shfl_xor(ss, 8);
    float rs = rsqrtf(ss + 1e-6f);
    #pragma unroll
    for (int j = 0; j < 8; j++) val[j] *= rs;
  }
  int h = tid >> 4, cc = (tid & 15) * 8;
  float* op = outp + (((size_t)(b * HH + h)) * TT + t) * 128 + cc;
  f32x4 o0, o1;
  #pragma unroll
  for (int j = 0; j < 4; j++) { o0[j] = val[j]; o1[j] = val[4 + j]; }
  *(f32x4*)op = o0;
  *(f32x4*)(op + 4) = o1;
}

// ---------------- beta = sigmoid(x @ Wb) -> [B,H,T] layout ----------------
__global__ __launch_bounds__(256) void beta_kernel(const float* __restrict__ x,
                                                   const float* __restrict__ Wb,
                                                   float* __restrict__ beta) {
  __shared__ float xs[2048];
  int bt = blockIdx.x, tid = threadIdx.x;
  int b = bt >> 11, t = bt & (TT - 1);
  const float* row = x + (size_t)bt * DD;
  #pragma unroll
  for (int i = 0; i < 2; i++)
    *(f32x4*)(xs + tid * 8 + i * 4) = *(const f32x4*)(row + tid * 8 + i * 4);
  __syncthreads();
  int h = tid >> 4, seg = tid & 15;
  float p = 0.f;
  for (int j = 0; j < 128; j++) {
    int d = seg * 128 + ((j + seg * 9) & 127);
    p += xs[d] * Wb[(size_t)d * HH + h];
  }
  p += __shfl_xor(p, 1); p += __shfl_xor(p, 2);
  p += __shfl_xor(p, 4); p += __shfl_xor(p, 8);
  if (seg == 0) beta[((size_t)(b * HH + h)) * TT + t] = 1.f / (1.f + expf(-p));
}

// ---------------- gexp -> [B,H,T,128] layout ----------------
__global__ __launch_bounds__(256) void gexp_kernel(const float* __restrict__ g,
                                                   const float* __restrict__ A_log,
                                                   const float* __restrict__ dt_bias,
                                                   float* __restrict__ ge, int n) {
  int i = blockIdx.x * 256 + threadIdx.x;
  if (i >= n) return;
  int bt = i >> 11, ch = i & (HD - 1);
  int b = bt >> 11, t = bt & (TT - 1);
  int h = ch >> 7, c = ch & 127;
  float gv = g[i] + dt_bias[ch];
  float sp = (gv > 20.f) ? gv : log1pf(expf(gv));
  ge[(((size_t)(b * HH + h)) * TT + t) * 128 + c] = expf(-expf(A_log[h]) * sp);
}

// ---------------- KDA delta-rule scan: chunked LDS pipeline ----------------
// Inputs in [B,H,T,128] ([B,H,T] for beta). One block per (b,h) x 16 columns.
// v and o alias (same buffer): block writes o rows strictly below rows it
// loads for the next chunk, and only reads its own 16 v-columns.
__global__ __launch_bounds__(256) void scan_kernel(const float* __restrict__ q,
                                                   const float* __restrict__ k,
                                                   const float* v,
                                                   const float* __restrict__ ge,
                                                   const float* __restrict__ beta,
                                                   float* o) {
  __shared__ __align__(16) float kbuf[2][SCH * 128];
  __shared__ __align__(16) float gbuf[2][SCH * 128];
  __shared__ __align__(16) float qbuf[2][SCH * 128];
  __shared__ __align__(16) float vbuf[2][SCH * 16];
  __shared__ __align__(16) float bbuf[TT];

  int blk = blockIdx.x;
  int colblk = blk & 7;
  int bh = blk >> 3;
  int tid = threadIdx.x;
  int w = tid >> 6, l = tid & 63;
  int grp = l >> 4, i = l & 15;
  int lcol = w * 4 + grp;                  // 0..15: column index within block
  int col = colblk * 16 + lcol;            // 0..127: column within head

  const float* kbh = k    + (size_t)bh * TT * 128;
  const float* gbh = ge   + (size_t)bh * TT * 128;
  const float* qbh = q    + (size_t)bh * TT * 128;
  const float* vbh = v    + (size_t)bh * TT * 128;
  const float* bbh = beta + (size_t)bh * TT;
  float* obh = o + (size_t)bh * TT * 128;

  // stage whole beta sequence (8 KB) once
  #pragma unroll
  for (int j = 0; j < 2; j++) {
    int jj = w * 2 + j;
    async_ld16(bbh + jj * 256 + l * 4, (float*)bbuf + jj * 256);
  }
  // stage chunk 0 into buffer 0 (wave w owns one operand; LDS base uniform)
  if (w == 0) {
    #pragma unroll
    for (int j = 0; j < 8; j++)
      async_ld16(kbh + j * 256 + l * 4, (float*)kbuf[0] + j * 256);
  } else if (w == 1) {
    #pragma unroll
    for (int j = 0; j < 8; j++)
      async_ld16(gbh + j * 256 + l * 4, (float*)gbuf[0] + j * 256);
  } else if (w == 2) {
    #pragma unroll
    for (int j = 0; j < 8; j++)
      async_ld16(qbh + j * 256 + l * 4, (float*)qbuf[0] + j * 256);
  } else {
    async_ld16(vbh + (size_t)(l >> 2) * 128 + colblk * 16 + (l & 3) * 4,
               (float*)vbuf[0]);
  }
  __syncthreads();

  f32x4 s0 = {0.f, 0.f, 0.f, 0.f}, s1 = {0.f, 0.f, 0.f, 0.f};
  const float scale = 0.08838834764831845f;  // 128^-0.5

  for (int c = 0; c < TT / SCH; c++) {
    int cb = c & 1, nb = cb ^ 1;
    // async-stage next chunk; latency hidden behind 16 compute steps
    if (c + 1 < TT / SCH) {
      size_t t0n = (size_t)(c + 1) * SCH;
      if (w == 0) {
        #pragma unroll
        for (int j = 0; j < 8; j++)
          async_ld16(kbh + t0n * 128 + j * 256 + l * 4, (float*)kbuf[nb] + j * 256);
      } else if (w == 1) {
        #pragma unroll
        for (int j = 0; j < 8; j++)
          async_ld16(gbh + t0n * 128 + j * 256 + l * 4, (float*)gbuf[nb] + j * 256);
      } else if (w == 2) {
        #pragma unroll
        for (int j = 0; j < 8; j++)
          async_ld16(qbh + t0n * 128 + j * 256 + l * 4, (float*)qbuf[nb] + j * 256);
      } else {
        async_ld16(vbh + (t0n + (l >> 2)) * 128 + colblk * 16 + (l & 3) * 4,
                   (float*)vbuf[nb]);
      }
    }
    // compute 16 steps from current buffer
    #pragma unroll
    for (int s = 0; s < SCH; s++) {
      const float* kp = (const float*)kbuf[cb] + s * 128 + i * 8;
      const float* gp = (const float*)gbuf[cb] + s * 128 + i * 8;
      const float* qp = (const float*)qbuf[cb] + s * 128 + i * 8;
      f32x4 k0 = *(const f32x4*)kp, k1 = *(const f32x4*)(kp + 4);
      f32x4 g0 = *(const f32x4*)gp, g1 = *(const f32x4*)(gp + 4);
      f32x4 q0 = *(const f32x4*)qp, q1 = *(const f32x4*)(qp + 4);
      float vt = ((const float*)vbuf[cb])[s * 16 + lcol];
      float bt = ((const float*)bbuf)[c * SCH + s];
      float p = 0.f;
      #pragma unroll
      for (int j = 0; j < 4; j++) {
        s0[j] *= g0[j]; p += k0[j] * s0[j];
        s1[j] *= g1[j]; p += k1[j] * s1[j];
      }
      p += __shfl_xor(p, 1); p += __shfl_xor(p, 2);
      p += __shfl_xor(p, 4); p += __shfl_xor(p, 8);
      float u = (vt - p) * bt;
      float po = 0.f;
      #pragma unroll
      for (int j = 0; j < 4; j++) {
        s0[j] += k0[j] * u; po += q0[j] * s0[j];
        s1[j] += k1[j] * u; po += q1[j] * s1[j];
      }
      po += __shfl_xor(po, 1); po += __shfl_xor(po, 2);
      po += __shfl_xor(po, 4); po += __shfl_xor(po, 8);
      if (i == 0) obh[((size_t)c * SCH + s) * 128 + col] = po * scale;
    }
    __syncthreads();
  }
}

// ---------------- gated RMSNorm -> bf16 (o in [B,H,T,128]) ----------------
__global__ __launch_bounds__(256) void out_norm_kernel(const float* o,
                                                       const float* __restrict__ gate,
                                                       const float* __restrict__ w,
                                                       unsigned short* __restrict__ onb) {
  int bt = blockIdx.x, tid = threadIdx.x;
  int b = bt >> 11, t = bt & (TT - 1);
  int h = tid >> 4, seg = tid & 15;
  size_t obase = (((size_t)(b * HH + h)) * TT + t) * 128 + seg * 8;
  size_t gbase = (size_t)bt * HD + (size_t)h * 128 + seg * 8;
  f32x4 o0 = *(const f32x4*)(o + obase);
  f32x4 o1 = *(const f32x4*)(o + obase + 4);
  float ss = 0.f;
  #pragma unroll
  for (int j = 0; j < 4; j++) ss += o0[j] * o0[j] + o1[j] * o1[j];
  ss += __shfl_xor(ss, 1); ss += __shfl_xor(ss, 2);
  ss += __shfl_xor(ss, 4); ss += __shfl_xor(ss, 8);
  float rs = rsqrtf(ss * (1.f / 128.f) + 1e-5f);
  u16x4 r0, r1;
  #pragma unroll
  for (int j = 0; j < 4; j++) {
    float gv0 = gate[gbase + j];
    float gv1 = gate[gbase + 4 + j];
    float a0 = o0[j] * rs * w[seg * 8 + j] * (gv0 / (1.f + expf(-gv0)));
    float a1 = o1[j] * rs * w[seg * 8 + 4 + j] * (gv1 / (1.f + expf(-gv1)));
    r0[j] = f2b(a0);
    r1[j] = f2b(a1);
  }
  *(u16x4*)(onb + gbase) = r0;
  *(u16x4*)(onb + gbase + 4) = r1;
}

// ---------------- driver ----------------
extern "C" void kernel_launch(void* const* d_in, const int* in_sizes, int n_in,
                              void* d_out, int out_size, void* d_ws, size_t ws_size,
                              hipStream_t stream) {
  const float* x       = (const float*)d_in[0];
  const float* Wq      = (const float*)d_in[1];
  const float* Wk      = (const float*)d_in[2];
  const float* Wv      = (const float*)d_in[3];
  const float* cq      = (const float*)d_in[4];
  const float* ck      = (const float*)d_in[5];
  const float* cv      = (const float*)d_in[6];
  const float* Wf1     = (const float*)d_in[7];
  const float* Wf2     = (const float*)d_in[8];
  const float* Wb      = (const float*)d_in[9];
  const float* A_log   = (const float*)d_in[10];
  const float* dt_bias = (const float*)d_in[11];
  const float* Wg      = (const float*)d_in[12];
  const float* bg      = (const float*)d_in[13];
  const float* onw     = (const float*)d_in[14];
  const float* Wo      = (const float*)d_in[15];
  float* out = (float*)d_out;

  char* ws = (char*)d_ws;
  unsigned short* WT  = (unsigned short*)(ws);                       //  8 MB rotating W^T
  unsigned short* xb  = (unsigned short*)(ws + ((size_t)8  << 20));  // 16 MB bf16 x
  float* P    = (float*)(ws + ((size_t)24  << 20));                  // 32 MB rotating pre/gate
  float* qb   = (float*)(ws + ((size_t)56  << 20));                  // 32 MB [B,H,T,128]
  float* kb   = (float*)(ws + ((size_t)88  << 20));                  // 32 MB [B,H,T,128]
  float* vb   = (float*)(ws + ((size_t)120 << 20));                  // 32 MB (aliased by o)
  float* geb  = (float*)(ws + ((size_t)152 << 20));                  // 32 MB [B,H,T,128]
  float* betab= (float*)(ws + ((size_t)184 << 20));                  // 256 KB [B,H,T]
  float* f1   = (float*)(ws + ((size_t)185 << 20));                  //   2 MB
  unsigned short* f1b = (unsigned short*)(ws + ((size_t)187 << 20)); //   1 MB
  unsigned short* onb = xb;   // xb dead after gate GEMM
  float* gateb = P;           // P reused as gate buffer
  float* ob    = vb;          // scan output aliases v

  dim3 tb(32, 8);
  dim3 gemm_grid(HD / 128, MM / 128);

  cast_f32_bf16<<<(MM * DD / 4 + 255) / 256, 256, 0, stream>>>(x, xb, MM * DD / 4);

  // q path
  transpose_cast<<<dim3(HD / 32, DD / 32), tb, 0, stream>>>(Wq, WT, DD, HD);
  gemm_bf16<<<gemm_grid, 256, 0, stream>>>(xb, WT, P, nullptr, MM, HD, DD);
  conv_silu_kernel<<<MM, 256, 0, stream>>>(P, cq, qb, 1);
  // k path
  transpose_cast<<<dim3(HD / 32, DD / 32), tb, 0, stream>>>(Wk, WT, DD, HD);
  gemm_bf16<<<gemm_grid, 256, 0, stream>>>(xb, WT, P, nullptr, MM, HD, DD);
  conv_silu_kernel<<<MM, 256, 0, stream>>>(P, ck, kb, 1);
  // v path
  transpose_cast<<<dim3(HD / 32, DD / 32), tb, 0, stream>>>(Wv, WT, DD, HD);
  gemm_bf16<<<gemm_grid, 256, 0, stream>>>(xb, WT, P, nullptr, MM, HD, DD);
  conv_silu_kernel<<<MM, 256, 0, stream>>>(P, cv, vb, 0);

  // beta
  beta_kernel<<<MM, 256, 0, stream>>>(x, Wb, betab);

  // g chain
  transpose_cast<<<dim3(128 / 32, DD / 32), tb, 0, stream>>>(Wf1, WT, DD, 128);
  gemm_bf16<<<dim3(1, MM / 128), 256, 0, stream>>>(xb, WT, f1, nullptr, MM, 128, DD);
  cast_f32_bf16<<<(MM * 128 / 4 + 255) / 256, 256, 0, stream>>>(f1, f1b, MM * 128 / 4);
  transpose_cast<<<dim3(HD / 32, 128 / 32), tb, 0, stream>>>(Wf2, WT, 128, HD);
  gemm_bf16<<<gemm_grid, 256, 0, stream>>>(f1b, WT, P, nullptr, MM, HD, 128);
  gexp_kernel<<<(MM * HD + 255) / 256, 256, 0, stream>>>(P, A_log, dt_bias, geb, MM * HD);

  // gate = x@Wg + bg
  transpose_cast<<<dim3(HD / 32, DD / 32), tb, 0, stream>>>(Wg, WT, DD, HD);
  gemm_bf16<<<gemm_grid, 256, 0, stream>>>(xb, WT, gateb, bg, MM, HD, DD);

  // chunked-pipeline delta-rule scan: one block per (b,h) x 16 columns
  scan_kernel<<<BB * HH * 8, 256, 0, stream>>>(qb, kb, vb, geb, betab, ob);

  // gated RMSNorm -> bf16
  out_norm_kernel<<<MM, 256, 0, stream>>>(ob, gateb, onw, onb);

  // final projection
  transpose_cast<<<dim3(DD / 32, HD / 32), tb, 0, stream>>>(Wo, WT, HD, DD);
  gemm_bf16<<<dim3(DD / 128, MM / 128), 256, 0, stream>>>(onb, WT, out, nullptr, MM, DD, HD);
}

// Round 3
// 1234.502 us; speedup vs baseline: 1.7585x; 1.4526x over previous
//
#include <hip/hip_runtime.h>
#include <stdint.h>

// Problem constants
#define BB 2
#define TT 2048
#define DD 2048
#define HH 16
#define HD 2048     // H*Dk = H*Dv
#define MM 4096     // B*T
#define SCH 16      // scan chunk steps

typedef float f32x4 __attribute__((ext_vector_type(4)));
typedef __bf16 bf16x8 __attribute__((ext_vector_type(8)));
typedef unsigned short u16x4 __attribute__((ext_vector_type(4)));

__device__ __forceinline__ unsigned short f2b(float f) {
  unsigned int u = __float_as_uint(f);
  u += 0x7FFFu + ((u >> 16) & 1u);   // RNE
  return (unsigned short)(u >> 16);
}

__device__ __forceinline__ void async_ld16(const void* g, void* l) {
  typedef __attribute__((address_space(3))) void as3_t;
  typedef const __attribute__((address_space(1))) void as1_t;
  // NOTE: LDS arg must be WAVE-UNIFORM base; HW adds lane*16 itself.
  __builtin_amdgcn_global_load_lds((as1_t*)(uintptr_t)g,
                                   (as3_t*)(unsigned int)(uintptr_t)l, 16, 0, 0);
}

// ---- DPP 16-lane all-reduce (VALU-pipe; avoids ds_swizzle ~120cyc latency) ----
template <int CTRL>
__device__ __forceinline__ float dpp_add(float x) {
  int y = __builtin_amdgcn_update_dpp(0, __float_as_int(x), CTRL, 0xF, 0xF, false);
  return x + __int_as_float(y);
}
__device__ __forceinline__ float reduce16(float x) {
  x = dpp_add<0xB1>(x);    // quad_perm [1,0,3,2]  (xor 1)
  x = dpp_add<0x4E>(x);    // quad_perm [2,3,0,1]  (xor 2)
  x = dpp_add<0x124>(x);   // row_ror:4
  x = dpp_add<0x128>(x);   // row_ror:8
  return x;                // all 16 lanes hold the row sum
}

// ---------------- cast f32 -> bf16 (vectorized x4) ----------------
__global__ __launch_bounds__(256) void cast_f32_bf16(const float* __restrict__ in,
                                                     unsigned short* __restrict__ out,
                                                     int n4) {
  int i = blockIdx.x * 256 + threadIdx.x;
  if (i >= n4) return;
  f32x4 v = *(const f32x4*)(in + (size_t)i * 4);
  u16x4 r;
  #pragma unroll
  for (int j = 0; j < 4; j++) r[j] = f2b(v[j]);
  *(u16x4*)(out + (size_t)i * 4) = r;
}

// ---------------- transpose + cast: in f32 [R,C] -> out bf16 [C,R] ----------------
__global__ __launch_bounds__(256) void transpose_cast(const float* __restrict__ in,
                                                      unsigned short* __restrict__ out,
                                                      int R, int C) {
  __shared__ float tile[32][33];
  int bx = blockIdx.x * 32, by = blockIdx.y * 32;
  int tx = threadIdx.x, ty = threadIdx.y;
  #pragma unroll
  for (int i = 0; i < 32; i += 8)
    tile[ty + i][tx] = in[(size_t)(by + ty + i) * C + bx + tx];
  __syncthreads();
  #pragma unroll
  for (int i = 0; i < 32; i += 8)
    out[(size_t)(bx + ty + i) * R + by + tx] = f2b(tile[tx][ty + i]);
}

// ---------------- bf16 GEMM: C[M,N] f32 = A[M,K] @ Bt[N,K]^T (+bias) ----------------
__global__ __launch_bounds__(256) void gemm_bf16(const unsigned short* __restrict__ A,
                                                 const unsigned short* __restrict__ Bt,
                                                 float* __restrict__ C,
                                                 const float* __restrict__ bias,
                                                 int M, int N, int K) {
  __shared__ __align__(16) unsigned short As[128 * 32];
  __shared__ __align__(16) unsigned short Bs[128 * 32];
  int tid = threadIdx.x;
  int l = tid & 63, w = tid >> 6;
  int row0 = blockIdx.y * 128, col0 = blockIdx.x * 128;
  int wm = (w >> 1) * 64, wn = (w & 1) * 64;
  const f32x4 fz = {0.f, 0.f, 0.f, 0.f};
  f32x4 acc[4][4];
  #pragma unroll
  for (int i = 0; i < 4; i++)
    #pragma unroll
    for (int j = 0; j < 4; j++) acc[i][j] = fz;

  int srow = l >> 2, skoff = (l & 3) * 8;
  int quad = l >> 4, mrow = l & 15;

  for (int kt = 0; kt < K; kt += 32) {
    #pragma unroll
    for (int i = 0; i < 2; i++) {
      int c = w * 2 + i;
      const unsigned short* gA = A + (size_t)(row0 + c * 16 + srow) * K + kt + skoff;
      const unsigned short* gB = Bt + (size_t)(col0 + c * 16 + srow) * K + kt + skoff;
      async_ld16(gA, As + c * 512);
      async_ld16(gB, Bs + c * 512);
    }
    __syncthreads();
    bf16x8 af[4], bfr[4];
    #pragma unroll
    for (int i = 0; i < 4; i++)
      af[i] = *(const bf16x8*)(As + (wm + i * 16 + mrow) * 32 + quad * 8);
    #pragma unroll
    for (int j = 0; j < 4; j++)
      bfr[j] = *(const bf16x8*)(Bs + (wn + j * 16 + mrow) * 32 + quad * 8);
    #pragma unroll
    for (int i = 0; i < 4; i++)
      #pragma unroll
      for (int j = 0; j < 4; j++)
        acc[i][j] = __builtin_amdgcn_mfma_f32_16x16x32_bf16(af[i], bfr[j], acc[i][j], 0, 0, 0);
    __syncthreads();
  }
  #pragma unroll
  for (int i = 0; i < 4; i++) {
    #pragma unroll
    for (int j = 0; j < 4; j++) {
      #pragma unroll
      for (int r = 0; r < 4; r++) {
        int rr = row0 + wm + i * 16 + quad * 4 + r;
        int cc = col0 + wn + j * 16 + mrow;
        float v = acc[i][j][r];
        if (bias) v += bias[cc];
        C[(size_t)rr * N + cc] = v;
      }
    }
  }
}

// ---------------- causal depthwise conv(K=4) + SiLU (+ per-head l2norm) ----------------
// Writes [B,H,T,128] layout for the scan.
__global__ __launch_bounds__(256) void conv_silu_kernel(const float* __restrict__ Pre,
                                                        const float* __restrict__ cw,
                                                        float* __restrict__ outp,
                                                        int do_norm) {
  int bt = blockIdx.x;
  int b = bt >> 11, t = bt & (TT - 1);
  int tid = threadIdx.x;
  int ch0 = tid * 8;
  f32x4 wv[8];
  #pragma unroll
  for (int j = 0; j < 8; j++) wv[j] = *(const f32x4*)(cw + (size_t)(ch0 + j) * 4);
  float acc[8] = {0, 0, 0, 0, 0, 0, 0, 0};
  #pragma unroll
  for (int i = 0; i < 4; i++) {
    int tt = t - 3 + i;
    if (tt < 0) continue;
    const float* r = Pre + ((size_t)(b * TT + tt)) * HD + ch0;
    f32x4 a0 = *(const f32x4*)r;
    f32x4 a1 = *(const f32x4*)(r + 4);
    #pragma unroll
    for (int j = 0; j < 4; j++) {
      acc[j]     += a0[j] * wv[j][i];
      acc[4 + j] += a1[j] * wv[4 + j][i];
    }
  }
  float val[8];
  #pragma unroll
  for (int j = 0; j < 8; j++) val[j] = acc[j] / (1.f + expf(-acc[j]));   // SiLU
  if (do_norm) {
    float ss = 0.f;
    #pragma unroll
    for (int j = 0; j < 8; j++) ss += val[j] * val[j];
    ss = reduce16(ss);
    float rs = rsqrtf(ss + 1e-6f);
    #pragma unroll
    for (int j = 0; j < 8; j++) val[j] *= rs;
  }
  int h = tid >> 4, cc = (tid & 15) * 8;
  float* op = outp + (((size_t)(b * HH + h)) * TT + t) * 128 + cc;
  f32x4 o0, o1;
  #pragma unroll
  for (int j = 0; j < 4; j++) { o0[j] = val[j]; o1[j] = val[4 + j]; }
  *(f32x4*)op = o0;
  *(f32x4*)(op + 4) = o1;
}

// ---------------- beta = sigmoid(x @ Wb) -> [B,H,T] layout ----------------
__global__ __launch_bounds__(256) void beta_kernel(const float* __restrict__ x,
                                                   const float* __restrict__ Wb,
                                                   float* __restrict__ beta) {
  __shared__ float xs[2048];
  int bt = blockIdx.x, tid = threadIdx.x;
  int b = bt >> 11, t = bt & (TT - 1);
  const float* row = x + (size_t)bt * DD;
  #pragma unroll
  for (int i = 0; i < 2; i++)
    *(f32x4*)(xs + tid * 8 + i * 4) = *(const f32x4*)(row + tid * 8 + i * 4);
  __syncthreads();
  int h = tid >> 4, seg = tid & 15;
  float p = 0.f;
  for (int j = 0; j < 128; j++) {
    int d = seg * 128 + ((j + seg * 9) & 127);
    p += xs[d] * Wb[(size_t)d * HH + h];
  }
  p = reduce16(p);
  if (seg == 0) beta[((size_t)(b * HH + h)) * TT + t] = 1.f / (1.f + expf(-p));
}

// ---------------- gexp -> [B,H,T,128] layout ----------------
__global__ __launch_bounds__(256) void gexp_kernel(const float* __restrict__ g,
                                                   const float* __restrict__ A_log,
                                                   const float* __restrict__ dt_bias,
                                                   float* __restrict__ ge, int n) {
  int i = blockIdx.x * 256 + threadIdx.x;
  if (i >= n) return;
  int bt = i >> 11, ch = i & (HD - 1);
  int b = bt >> 11, t = bt & (TT - 1);
  int h = ch >> 7, c = ch & 127;
  float gv = g[i] + dt_bias[ch];
  float sp = (gv > 20.f) ? gv : log1pf(expf(gv));
  ge[(((size_t)(b * HH + h)) * TT + t) * 128 + c] = expf(-expf(A_log[h]) * sp);
}

// ---------------- KDA delta-rule scan: chunked LDS pipeline + DPP reduce ----------------
// Inputs in [B,H,T,128] ([B,H,T] for beta). One block per (b,h) x 16 columns.
// v and o alias: block only touches its own 16 columns; writes strictly behind reads.
__global__ __launch_bounds__(256) void scan_kernel(const float* __restrict__ q,
                                                   const float* __restrict__ k,
                                                   const float* v,
                                                   const float* __restrict__ ge,
                                                   const float* __restrict__ beta,
                                                   float* o) {
  __shared__ __align__(16) float kbuf[2][SCH * 128];
  __shared__ __align__(16) float gbuf[2][SCH * 128];
  __shared__ __align__(16) float qbuf[2][SCH * 128];
  __shared__ __align__(16) float vbuf[2][SCH * 16];
  __shared__ __align__(16) float bbuf[TT];

  int blk = blockIdx.x;
  int colblk = blk & 7;
  int bh = blk >> 3;
  int tid = threadIdx.x;
  int w = tid >> 6, l = tid & 63;
  int grp = l >> 4, i = l & 15;
  int lcol = w * 4 + grp;                  // 0..15: column index within block
  int col = colblk * 16 + lcol;            // 0..127: column within head

  const float* kbh = k    + (size_t)bh * TT * 128;
  const float* gbh = ge   + (size_t)bh * TT * 128;
  const float* qbh = q    + (size_t)bh * TT * 128;
  const float* vbh = v    + (size_t)bh * TT * 128;
  const float* bbh = beta + (size_t)bh * TT;
  float* obh = o + (size_t)bh * TT * 128;

  // stage whole beta sequence (8 KB) once
  #pragma unroll
  for (int j = 0; j < 2; j++) {
    int jj = w * 2 + j;
    async_ld16(bbh + jj * 256 + l * 4, (float*)bbuf + jj * 256);
  }
  // stage chunk 0 into buffer 0 (wave w owns one operand; LDS base uniform)
  if (w == 0) {
    #pragma unroll
    for (int j = 0; j < 8; j++)
      async_ld16(kbh + j * 256 + l * 4, (float*)kbuf[0] + j * 256);
  } else if (w == 1) {
    #pragma unroll
    for (int j = 0; j < 8; j++)
      async_ld16(gbh + j * 256 + l * 4, (float*)gbuf[0] + j * 256);
  } else if (w == 2) {
    #pragma unroll
    for (int j = 0; j < 8; j++)
      async_ld16(qbh + j * 256 + l * 4, (float*)qbuf[0] + j * 256);
  } else {
    async_ld16(vbh + (size_t)(l >> 2) * 128 + colblk * 16 + (l & 3) * 4,
               (float*)vbuf[0]);
  }
  __syncthreads();

  f32x4 s0 = {0.f, 0.f, 0.f, 0.f}, s1 = {0.f, 0.f, 0.f, 0.f};
  const float scale = 0.08838834764831845f;  // 128^-0.5

  for (int c = 0; c < TT / SCH; c++) {
    int cb = c & 1, nb = cb ^ 1;
    // async-stage next chunk; latency hidden behind 16 compute steps
    if (c + 1 < TT / SCH) {
      size_t t0n = (size_t)(c + 1) * SCH;
      if (w == 0) {
        #pragma unroll
        for (int j = 0; j < 8; j++)
          async_ld16(kbh + t0n * 128 + j * 256 + l * 4, (float*)kbuf[nb] + j * 256);
      } else if (w == 1) {
        #pragma unroll
        for (int j = 0; j < 8; j++)
          async_ld16(gbh + t0n * 128 + j * 256 + l * 4, (float*)gbuf[nb] + j * 256);
      } else if (w == 2) {
        #pragma unroll
        for (int j = 0; j < 8; j++)
          async_ld16(qbh + t0n * 128 + j * 256 + l * 4, (float*)qbuf[nb] + j * 256);
      } else {
        async_ld16(vbh + (t0n + (l >> 2)) * 128 + colblk * 16 + (l & 3) * 4,
                   (float*)vbuf[nb]);
      }
    }
    const float* kc = (const float*)kbuf[cb];
    const float* gc = (const float*)gbuf[cb];
    const float* qc = (const float*)qbuf[cb];
    // register-rotate: load step s+1 while computing step s
    f32x4 k0 = *(const f32x4*)(kc + i * 8), k1 = *(const f32x4*)(kc + i * 8 + 4);
    f32x4 g0 = *(const f32x4*)(gc + i * 8), g1 = *(const f32x4*)(gc + i * 8 + 4);
    f32x4 q0 = *(const f32x4*)(qc + i * 8), q1 = *(const f32x4*)(qc + i * 8 + 4);
    #pragma unroll
    for (int s = 0; s < SCH; s++) {
      f32x4 k0n, k1n, g0n, g1n, q0n, q1n;
      if (s + 1 < SCH) {
        const float* kp = kc + (s + 1) * 128 + i * 8;
        const float* gp = gc + (s + 1) * 128 + i * 8;
        const float* qp = qc + (s + 1) * 128 + i * 8;
        k0n = *(const f32x4*)kp; k1n = *(const f32x4*)(kp + 4);
        g0n = *(const f32x4*)gp; g1n = *(const f32x4*)(gp + 4);
        q0n = *(const f32x4*)qp; q1n = *(const f32x4*)(qp + 4);
      }
      float vt = ((const float*)vbuf[cb])[s * 16 + lcol];
      float bt = ((const float*)bbuf)[c * SCH + s];
      s0 *= g0; s1 *= g1;                       // per-key-channel decay
      f32x4 pp = k0 * s0 + k1 * s1;             // packed-f32 FMA
      float p = (pp[0] + pp[1]) + (pp[2] + pp[3]);
      p = reduce16(p);                          // DPP butterfly, ~40 cyc
      float u = (vt - p) * bt;
      s0 += k0 * u; s1 += k1 * u;
      f32x4 oo = q0 * s0 + q1 * s1;
      float po = (oo[0] + oo[1]) + (oo[2] + oo[3]);
      po = reduce16(po);
      if (i == 0) obh[((size_t)c * SCH + s) * 128 + col] = po * scale;
      if (s + 1 < SCH) {
        k0 = k0n; k1 = k1n; g0 = g0n; g1 = g1n; q0 = q0n; q1 = q1n;
      }
    }
    __syncthreads();
  }
}

// ---------------- gated RMSNorm -> bf16 (o in [B,H,T,128]) ----------------
__global__ __launch_bounds__(256) void out_norm_kernel(const float* o,
                                                       const float* __restrict__ gate,
                                                       const float* __restrict__ w,
                                                       unsigned short* __restrict__ onb) {
  int bt = blockIdx.x, tid = threadIdx.x;
  int b = bt >> 11, t = bt & (TT - 1);
  int h = tid >> 4, seg = tid & 15;
  size_t obase = (((size_t)(b * HH + h)) * TT + t) * 128 + seg * 8;
  size_t gbase = (size_t)bt * HD + (size_t)h * 128 + seg * 8;
  f32x4 o0 = *(const f32x4*)(o + obase);
  f32x4 o1 = *(const f32x4*)(o + obase + 4);
  float ss = 0.f;
  #pragma unroll
  for (int j = 0; j < 4; j++) ss += o0[j] * o0[j] + o1[j] * o1[j];
  ss = reduce16(ss);
  float rs = rsqrtf(ss * (1.f / 128.f) + 1e-5f);
  u16x4 r0, r1;
  #pragma unroll
  for (int j = 0; j < 4; j++) {
    float gv0 = gate[gbase + j];
    float gv1 = gate[gbase + 4 + j];
    float a0 = o0[j] * rs * w[seg * 8 + j] * (gv0 / (1.f + expf(-gv0)));
    float a1 = o1[j] * rs * w[seg * 8 + 4 + j] * (gv1 / (1.f + expf(-gv1)));
    r0[j] = f2b(a0);
    r1[j] = f2b(a1);
  }
  *(u16x4*)(onb + gbase) = r0;
  *(u16x4*)(onb + gbase + 4) = r1;
}

// ---------------- driver ----------------
extern "C" void kernel_launch(void* const* d_in, const int* in_sizes, int n_in,
                              void* d_out, int out_size, void* d_ws, size_t ws_size,
                              hipStream_t stream) {
  const float* x       = (const float*)d_in[0];
  const float* Wq      = (const float*)d_in[1];
  const float* Wk      = (const float*)d_in[2];
  const float* Wv      = (const float*)d_in[3];
  const float* cq      = (const float*)d_in[4];
  const float* ck      = (const float*)d_in[5];
  const float* cv      = (const float*)d_in[6];
  const float* Wf1     = (const float*)d_in[7];
  const float* Wf2     = (const float*)d_in[8];
  const float* Wb      = (const float*)d_in[9];
  const float* A_log   = (const float*)d_in[10];
  const float* dt_bias = (const float*)d_in[11];
  const float* Wg      = (const float*)d_in[12];
  const float* bg      = (const float*)d_in[13];
  const float* onw     = (const float*)d_in[14];
  const float* Wo      = (const float*)d_in[15];
  float* out = (float*)d_out;

  char* ws = (char*)d_ws;
  unsigned short* WT  = (unsigned short*)(ws);                       //  8 MB rotating W^T
  unsigned short* xb  = (unsigned short*)(ws + ((size_t)8  << 20));  // 16 MB bf16 x
  float* P    = (float*)(ws + ((size_t)24  << 20));                  // 32 MB rotating pre/gate
  float* qb   = (float*)(ws + ((size_t)56  << 20));                  // 32 MB [B,H,T,128]
  float* kb   = (float*)(ws + ((size_t)88  << 20));                  // 32 MB [B,H,T,128]
  float* vb   = (float*)(ws + ((size_t)120 << 20));                  // 32 MB (aliased by o)
  float* geb  = (float*)(ws + ((size_t)152 << 20));                  // 32 MB [B,H,T,128]
  float* betab= (float*)(ws + ((size_t)184 << 20));                  // 256 KB [B,H,T]
  float* f1   = (float*)(ws + ((size_t)185 << 20));                  //   2 MB
  unsigned short* f1b = (unsigned short*)(ws + ((size_t)187 << 20)); //   1 MB
  unsigned short* onb = xb;   // xb dead after gate GEMM
  float* gateb = P;           // P reused as gate buffer
  float* ob    = vb;          // scan output aliases v

  dim3 tb(32, 8);
  dim3 gemm_grid(HD / 128, MM / 128);

  cast_f32_bf16<<<(MM * DD / 4 + 255) / 256, 256, 0, stream>>>(x, xb, MM * DD / 4);

  // q path
  transpose_cast<<<dim3(HD / 32, DD / 32), tb, 0, stream>>>(Wq, WT, DD, HD);
  gemm_bf16<<<gemm_grid, 256, 0, stream>>>(xb, WT, P, nullptr, MM, HD, DD);
  conv_silu_kernel<<<MM, 256, 0, stream>>>(P, cq, qb, 1);
  // k path
  transpose_cast<<<dim3(HD / 32, DD / 32), tb, 0, stream>>>(Wk, WT, DD, HD);
  gemm_bf16<<<gemm_grid, 256, 0, stream>>>(xb, WT, P, nullptr, MM, HD, DD);
  conv_silu_kernel<<<MM, 256, 0, stream>>>(P, ck, kb, 1);
  // v path
  transpose_cast<<<dim3(HD / 32, DD / 32), tb, 0, stream>>>(Wv, WT, DD, HD);
  gemm_bf16<<<gemm_grid, 256, 0, stream>>>(xb, WT, P, nullptr, MM, HD, DD);
  conv_silu_kernel<<<MM, 256, 0, stream>>>(P, cv, vb, 0);

  // beta
  beta_kernel<<<MM, 256, 0, stream>>>(x, Wb, betab);

  // g chain
  transpose_cast<<<dim3(128 / 32, DD / 32), tb, 0, stream>>>(Wf1, WT, DD, 128);
  gemm_bf16<<<dim3(1, MM / 128), 256, 0, stream>>>(xb, WT, f1, nullptr, MM, 128, DD);
  cast_f32_bf16<<<(MM * 128 / 4 + 255) / 256, 256, 0, stream>>>(f1, f1b, MM * 128 / 4);
  transpose_cast<<<dim3(HD / 32, 128 / 32), tb, 0, stream>>>(Wf2, WT, 128, HD);
  gemm_bf16<<<gemm_grid, 256, 0, stream>>>(f1b, WT, P, nullptr, MM, HD, 128);
  gexp_kernel<<<(MM * HD + 255) / 256, 256, 0, stream>>>(P, A_log, dt_bias, geb, MM * HD);

  // gate = x@Wg + bg
  transpose_cast<<<dim3(HD / 32, DD / 32), tb, 0, stream>>>(Wg, WT, DD, HD);
  gemm_bf16<<<gemm_grid, 256, 0, stream>>>(xb, WT, gateb, bg, MM, HD, DD);

  // chunked-pipeline delta-rule scan
  scan_kernel<<<BB * HH * 8, 256, 0, stream>>>(qb, kb, vb, geb, betab, ob);

  // gated RMSNorm -> bf16
  out_norm_kernel<<<MM, 256, 0, stream>>>(ob, gateb, onw, onb);

  // final projection
  transpose_cast<<<dim3(DD / 32, HD / 32), tb, 0, stream>>>(Wo, WT, HD, DD);
  gemm_bf16<<<dim3(DD / 128, MM / 128), 256, 0, stream>>>(onb, WT, out, nullptr, MM, DD, HD);
}